// Round 1
// baseline (3429.596 us; speedup 1.0000x reference)
//
#include <hip/hip_runtime.h>
#include <cstdint>

static constexpr int N = 20000;
static constexpr int E = 320000;
static constexpr int R = 8;
static constexpr int H = 4;
static constexpr int C = 256;

__device__ __forceinline__ float lrelu(float x, float s) { return x >= 0.f ? x : s * x; }
__device__ __forceinline__ unsigned fenc(float f) {
    unsigned u = __float_as_uint(f);
    return (u & 0x80000000u) ? ~u : (u | 0x80000000u);
}
__device__ __forceinline__ float fdec(unsigned u) {
    unsigned v = (u & 0x80000000u) ? (u & 0x7FFFFFFFu) : ~u;
    return __uint_as_float(v);
}

__global__ void k_fill(float* p, float v, int n) {
    int i = blockIdx.x * blockDim.x + threadIdx.x;
    if (i < n) p[i] = v;
}

__global__ void k_deg(const int* __restrict__ ei, float* deg) {
    int e = blockIdx.x * blockDim.x + threadIdx.x;
    if (e < E) atomicAdd(&deg[ei[E + e]], 1.0f);
}

__global__ void k_rsqrt(float* p, int n) {
    int i = blockIdx.x * blockDim.x + threadIdx.x;
    if (i < n) p[i] = rsqrtf(p[i]);
}

// h1 = ccle0 @ W1   [N,32]
__global__ void k_h1(const float* __restrict__ x, const float* __restrict__ W,
                     float* __restrict__ h) {
    int idx = blockIdx.x * blockDim.x + threadIdx.x;
    if (idx >= N * 32) return;
    int n = idx >> 5, f = idx & 31;
    const float* xr = x + n * 4;
    float acc = 0.f;
#pragma unroll
    for (int c = 0; c < 4; ++c) acc += xr[c] * W[c * 32 + f];
    h[idx] = acc;
}

// c1 = dis^2 * h1 + b1  (self-loop term + bias)
__global__ void k_selfinit32(const float* __restrict__ h, const float* __restrict__ dis,
                             const float* __restrict__ b, float* __restrict__ c) {
    int idx = blockIdx.x * blockDim.x + threadIdx.x;
    if (idx >= N * 32) return;
    int n = idx >> 5, f = idx & 31;
    float d = dis[n];
    c[idx] = d * d * h[idx] + b[f];
}

__global__ void k_gcn_scatter32(const int* __restrict__ ei, const float* __restrict__ dis,
                                const float* __restrict__ h, float* __restrict__ c) {
    int idx = blockIdx.x * blockDim.x + threadIdx.x;
    if (idx >= E * 32) return;
    int e = idx >> 5, f = idx & 31;
    int s = ei[e], d = ei[E + e];
    atomicAdd(&c[d * 32 + f], dis[s] * dis[d] * h[s * 32 + f]);
}

// h2 = leaky(c1) @ W2  [N,128]
__global__ void k_h2(const float* __restrict__ c1, const float* __restrict__ W,
                     float* __restrict__ h) {
    int idx = blockIdx.x * blockDim.x + threadIdx.x;
    if (idx >= N * 128) return;
    int n = idx >> 7, f = idx & 127;
    const float* cr = c1 + n * 32;
    float acc = 0.f;
    for (int c = 0; c < 32; ++c) acc += lrelu(cr[c], 0.01f) * W[c * 128 + f];
    h[idx] = acc;
}

// x0[:, :128] = kg ; x0[:, 128:] = dis^2*h2 + b2  (self-loop init of GCN2)
__global__ void k_x0init(const float* __restrict__ kg, const float* __restrict__ h2,
                         const float* __restrict__ dis, const float* __restrict__ b,
                         float* __restrict__ x0) {
    int idx = blockIdx.x * blockDim.x + threadIdx.x;
    if (idx >= N * 256) return;
    int n = idx >> 8, f = idx & 255;
    float v;
    if (f < 128) v = kg[n * 128 + f];
    else { float d = dis[n]; v = d * d * h2[n * 128 + (f - 128)] + b[f - 128]; }
    x0[idx] = v;
}

__global__ void k_gcn_scatter128(const int* __restrict__ ei, const float* __restrict__ dis,
                                 const float* __restrict__ h, float* __restrict__ x0) {
    long idx = (long)blockIdx.x * blockDim.x + threadIdx.x;
    if (idx >= (long)E * 128) return;
    int e = (int)(idx >> 7), f = (int)(idx & 127);
    int s = ei[e], d = ei[E + e];
    atomicAdd(&x0[d * 256 + 128 + f], dis[s] * dis[d] * h[s * 128 + f]);
}

// wq[i*32 + r*4 + h] = sum_o W[r][i][o]*q[o][h] ; same for wk
__global__ void k_wqk(const float* __restrict__ W, const float* __restrict__ q,
                      const float* __restrict__ kmat, float* __restrict__ wq,
                      float* __restrict__ wk) {
    int idx = blockIdx.x * blockDim.x + threadIdx.x;
    if (idx >= R * 256 * H) return;
    int r = idx >> 10, i = (idx >> 2) & 255, h = idx & 3;
    const float* wr = W + ((long)r * 256 + i) * 256;
    float aq = 0.f, ak = 0.f;
    for (int o = 0; o < 256; ++o) {
        float wv = wr[o];
        aq += wv * q[o * 4 + h];
        ak += wv * kmat[o * 4 + h];
    }
    wq[i * 32 + r * 4 + h] = aq;
    wk[i * 32 + r * 4 + h] = ak;
}

// qn[n*32 + r*4 + h] = x[n] . wq[:,r,h]
__global__ void k_qnkn(const float* __restrict__ x, const float* __restrict__ wq,
                       const float* __restrict__ wk, float* __restrict__ qn,
                       float* __restrict__ kn) {
    int idx = blockIdx.x * blockDim.x + threadIdx.x;
    if (idx >= N * 32) return;
    int n = idx >> 5, rh = idx & 31;
    const float* xr = x + (long)n * 256;
    float aq = 0.f, ak = 0.f;
    for (int i = 0; i < 256; ++i) {
        float xv = xr[i];
        aq += xv * wq[i * 32 + rh];
        ak += xv * wk[i * 32 + rh];
    }
    qn[idx] = aq;
    kn[idx] = ak;
}

__global__ void k_initrow(const float* __restrict__ b, float* __restrict__ o, int n) {
    int idx = blockIdx.x * blockDim.x + threadIdx.x;
    if (idx < n) o[idx] = b[idx & 255];
}

__global__ void k_initmax(unsigned* __restrict__ amax, float* __restrict__ denom) {
    int idx = blockIdx.x * blockDim.x + threadIdx.x;
    if (idx < N * H) { amax[idx] = 0x007FFFFFu; denom[idx] = 0.f; }
}

__global__ void k_att1(const int* __restrict__ ei, const int* __restrict__ et,
                       const float* __restrict__ qn, const float* __restrict__ kn,
                       float* __restrict__ aout, unsigned* __restrict__ amax) {
    int idx = blockIdx.x * blockDim.x + threadIdx.x;
    if (idx >= E * H) return;
    int e = idx >> 2, h = idx & 3;
    int t = et[e], s = ei[e], d = ei[E + e];
    float v = qn[d * 32 + t * 4 + h] + kn[s * 32 + t * 4 + h];
    v = lrelu(v, 0.2f);
    aout[idx] = v;
    atomicMax(&amax[d * 4 + h], fenc(v));
}

__global__ void k_att2(const int* __restrict__ ei, float* __restrict__ aout,
                       const unsigned* __restrict__ amax, float* __restrict__ denom) {
    int idx = blockIdx.x * blockDim.x + threadIdx.x;
    if (idx >= E * H) return;
    int e = idx >> 2, h = idx & 3;
    int d = ei[E + e];
    float ex = expf(aout[idx] - fdec(amax[d * 4 + h]));
    aout[idx] = ex;
    atomicAdd(&denom[d * 4 + h], ex);
}

__global__ void k_att3(const int* __restrict__ ei, float* __restrict__ aout,
                       const float* __restrict__ denom) {
    int idx = blockIdx.x * blockDim.x + threadIdx.x;
    if (idx >= E * H) return;
    int e = idx >> 2, h = idx & 3;
    int d = ei[E + e];
    aout[idx] = aout[idx] / denom[d * 4 + h];
}

// one wave per edge; lane covers 4 floats of the 256-wide message
__global__ void k_msg(const int* __restrict__ ei, const int* __restrict__ et,
                      const float* __restrict__ alpha, const float* __restrict__ xw,
                      float* __restrict__ out, int r0, int r1) {
    int gid = blockIdx.x * blockDim.x + threadIdx.x;
    int e = gid >> 6, lane = gid & 63;
    if (e >= E) return;
    int t = et[e];
    if (t < r0 || t >= r1) return;
    int s = ei[e], d = ei[E + e];
    float a = alpha[e * 4 + (lane >> 4)];
    float4 v = ((const float4*)(xw + ((long)(t - r0) * N + s) * 256))[lane];
    float* o = out + (long)d * 256 + lane * 4;
    atomicAdd(o + 0, a * v.x);
    atomicAdd(o + 1, a * v.y);
    atomicAdd(o + 2, a * v.z);
    atomicAdd(o + 3, a * v.w);
}

__global__ void k_leaky(float* p, int n) {
    int i = blockIdx.x * blockDim.x + threadIdx.x;
    if (i < n) p[i] = lrelu(p[i], 0.01f);
}

// C[z] = A @ B[z] (+bias) (+C existing).  A:[M,K] row-major, B:[K,Nc], C:[M,Nc]
#define BM 64
#define BN 64
#define BKT 16
__global__ __launch_bounds__(256) void gemm_kernel(
    const float* __restrict__ A, const float* __restrict__ B,
    float* __restrict__ Cmat, const float* __restrict__ bias,
    int M, int K, int Nc, long strideB, long strideC, int addC)
{
    const float* Bp = B + (long)blockIdx.z * strideB;
    float* Cp = Cmat + (long)blockIdx.z * strideC;
    int m0 = blockIdx.y * BM;
    int n0 = blockIdx.x * BN;
    __shared__ float As[BKT][BM + 1];
    __shared__ float Bs[BKT][BN];
    int t = threadIdx.x;
    int tx = t & 15, ty = t >> 4;
    float acc[4][4] = {};
    for (int k0 = 0; k0 < K; k0 += BKT) {
#pragma unroll
        for (int i = 0; i < 4; ++i) {
            int idx = t + i * 256;
            int m = idx >> 4, kk = idx & 15;
            int gm = m0 + m;
            As[kk][m] = (gm < M) ? A[(long)gm * K + k0 + kk] : 0.f;
        }
#pragma unroll
        for (int i = 0; i < 4; ++i) {
            int idx = t + i * 256;
            int kk = idx >> 6, n = idx & 63;
            Bs[kk][n] = Bp[(long)(k0 + kk) * Nc + n0 + n];
        }
        __syncthreads();
#pragma unroll
        for (int kk = 0; kk < BKT; ++kk) {
            float ar[4], br[4];
#pragma unroll
            for (int i = 0; i < 4; ++i) ar[i] = As[kk][ty * 4 + i];
#pragma unroll
            for (int j = 0; j < 4; ++j) br[j] = Bs[kk][tx * 4 + j];
#pragma unroll
            for (int i = 0; i < 4; ++i)
#pragma unroll
                for (int j = 0; j < 4; ++j)
                    acc[i][j] += ar[i] * br[j];
        }
        __syncthreads();
    }
#pragma unroll
    for (int i = 0; i < 4; ++i) {
        int gm = m0 + ty * 4 + i;
        if (gm >= M) continue;
#pragma unroll
        for (int j = 0; j < 4; ++j) {
            int gn = n0 + tx * 4 + j;
            float v = acc[i][j];
            if (bias) v += bias[gn];
            if (addC) v += Cp[(long)gm * Nc + gn];
            Cp[(long)gm * Nc + gn] = v;
        }
    }
}

extern "C" void kernel_launch(void* const* d_in, const int* in_sizes, int n_in,
                              void* d_out, int out_size, void* d_ws, size_t ws_size,
                              hipStream_t stream) {
    const float* kg   = (const float*)d_in[0];
    const float* cc0  = (const float*)d_in[1];
    const float* gw1  = (const float*)d_in[2];
    const float* gb1  = (const float*)d_in[3];
    const float* gw2  = (const float*)d_in[4];
    const float* gb2  = (const float*)d_in[5];
    const float* r1w  = (const float*)d_in[6];
    const float* r1q  = (const float*)d_in[7];
    const float* r1k  = (const float*)d_in[8];
    const float* r1b  = (const float*)d_in[9];
    const float* r2w  = (const float*)d_in[10];
    const float* r2q  = (const float*)d_in[11];
    const float* r2k  = (const float*)d_in[12];
    const float* r2b  = (const float*)d_in[13];
    const float* linw = (const float*)d_in[14];
    const float* linb = (const float*)d_in[15];
    const int*   ei   = (const int*)d_in[16];
    const int*   et   = (const int*)d_in[17];

    float* out = (float*)d_out;
    float* a1  = out + (size_t)N * C;
    float* a2  = a1 + (size_t)E * H;

    float* ws = (float*)d_ws;
    size_t off = 0;
    float* dis  = ws + off; off += N;
    float* h1   = ws + off; off += (size_t)N * 32;
    float* c1   = ws + off; off += (size_t)N * 32;
    float* h2   = ws + off; off += (size_t)N * 128;
    float* x0   = ws + off; off += (size_t)N * C;
    float* hmid = ws + off; off += (size_t)N * C;
    float* qn   = ws + off; off += (size_t)N * R * H;
    float* kn   = ws + off; off += (size_t)N * R * H;
    float* wq   = ws + off; off += (size_t)R * 256 * H;
    float* wk   = ws + off; off += (size_t)R * 256 * H;
    unsigned* amax = (unsigned*)(ws + off); off += (size_t)N * H;
    float* denom = ws + off; off += (size_t)N * H;
    float* xw   = ws + off;

    size_t fixedB = off * 4;
    int K = R;  // relations materialized per chunk (shrinks if ws is small)
    if (ws_size > fixedB) {
        size_t kmax = (ws_size - fixedB) / ((size_t)N * C * 4);
        if (kmax < (size_t)K) K = (int)kmax;
    } else {
        K = 1;
    }
    if (K < 1) K = 1;

    const int B = 256;
    auto cdiv = [](long a, long b) { return (int)((a + b - 1) / b); };

    // degree / symmetric-norm scale
    k_fill<<<cdiv(N, B), B, 0, stream>>>(dis, 1.0f, N);
    k_deg<<<cdiv(E, B), B, 0, stream>>>(ei, dis);
    k_rsqrt<<<cdiv(N, B), B, 0, stream>>>(dis, N);
    // GCN1: 4->32
    k_h1<<<cdiv((long)N * 32, B), B, 0, stream>>>(cc0, gw1, h1);
    k_selfinit32<<<cdiv((long)N * 32, B), B, 0, stream>>>(h1, dis, gb1, c1);
    k_gcn_scatter32<<<cdiv((long)E * 32, B), B, 0, stream>>>(ei, dis, h1, c1);
    // GCN2: 32->128 (leaky fused into k_h2 read)
    k_h2<<<cdiv((long)N * 128, B), B, 0, stream>>>(c1, gw2, h2);
    k_x0init<<<cdiv((long)N * C, B), B, 0, stream>>>(kg, h2, dis, gb2, x0);
    k_gcn_scatter128<<<cdiv((long)E * 128, B), B, 0, stream>>>(ei, dis, h2, x0);

    auto rgat = [&](const float* xin, const float* W, const float* q, const float* kk,
                    const float* b, float* obuf, float* aout) {
        k_wqk<<<cdiv((long)R * 256 * H, B), B, 0, stream>>>(W, q, kk, wq, wk);
        k_qnkn<<<cdiv((long)N * R * H, B), B, 0, stream>>>(xin, wq, wk, qn, kn);
        k_initrow<<<cdiv((long)N * C, B), B, 0, stream>>>(b, obuf, N * C);
        k_initmax<<<cdiv((long)N * H, B), B, 0, stream>>>(amax, denom);
        k_att1<<<cdiv((long)E * H, B), B, 0, stream>>>(ei, et, qn, kn, aout, amax);
        k_att2<<<cdiv((long)E * H, B), B, 0, stream>>>(ei, aout, amax, denom);
        k_att3<<<cdiv((long)E * H, B), B, 0, stream>>>(ei, aout, denom);
        for (int r0 = 0; r0 < R; r0 += K) {
            int kc = (R - r0) < K ? (R - r0) : K;
            dim3 g(C / 64, cdiv(N, 64), kc);
            gemm_kernel<<<g, 256, 0, stream>>>(xin, W + (long)r0 * C * C, xw, nullptr,
                                               N, C, C, (long)C * C, (long)N * C, 0);
            k_msg<<<cdiv((long)E * 64, B), B, 0, stream>>>(ei, et, aout, xw, obuf,
                                                           r0, r0 + kc);
        }
    };

    rgat(x0, r1w, r1q, r1k, r1b, hmid, a1);
    k_leaky<<<cdiv((long)N * C, B), B, 0, stream>>>(hmid, N * C);
    rgat(hmid, r2w, r2q, r2k, r2b, out, a2);

    // out += x0 @ lin_w + lin_b
    dim3 g(C / 64, cdiv(N, 64), 1);
    gemm_kernel<<<g, 256, 0, stream>>>(x0, linw, out, linb, N, C, C, 0, 0, 1);
}

// Round 2
// 1394.404 us; speedup vs baseline: 2.4595x; 2.4595x over previous
//
#include <hip/hip_runtime.h>
#include <cstdint>

static constexpr int N = 20000;
static constexpr int E = 320000;
static constexpr int R = 8;
static constexpr int H = 4;
static constexpr int C = 256;

__device__ __forceinline__ float lrelu(float x, float s) { return x >= 0.f ? x : s * x; }
__device__ __forceinline__ unsigned fenc(float f) {
    unsigned u = __float_as_uint(f);
    return (u & 0x80000000u) ? ~u : (u | 0x80000000u);
}
__device__ __forceinline__ float fdec(unsigned u) {
    unsigned v = (u & 0x80000000u) ? (u & 0x7FFFFFFFu) : ~u;
    return __uint_as_float(v);
}

// ---------------- CSR build ----------------
__global__ void k_zero_int(int* p, int n) {
    int i = blockIdx.x * blockDim.x + threadIdx.x;
    if (i < n) p[i] = 0;
}

__global__ void k_count(const int* __restrict__ ei, int* __restrict__ cnt) {
    int e = blockIdx.x * blockDim.x + threadIdx.x;
    if (e < E) atomicAdd(&cnt[ei[E + e]], 1);
}

// single-block exclusive scan of cnt[0..N) -> rowptr[0..N]
__global__ __launch_bounds__(1024) void k_scan(const int* __restrict__ cnt,
                                               int* __restrict__ rowptr) {
    __shared__ int part[1024];
    const int CH = (N + 1023) / 1024;  // 20
    int t = threadIdx.x;
    int base = t * CH;
    int sum = 0;
    for (int j = 0; j < CH; ++j) {
        int idx = base + j;
        if (idx < N) sum += cnt[idx];
    }
    part[t] = sum;
    __syncthreads();
    for (int off = 1; off < 1024; off <<= 1) {
        int v = 0;
        if (t >= off) v = part[t - off];
        __syncthreads();
        if (t >= off) part[t] += v;
        __syncthreads();
    }
    int run = part[t] - sum;  // exclusive prefix
    for (int j = 0; j < CH; ++j) {
        int idx = base + j;
        if (idx < N) { rowptr[idx] = run; run += cnt[idx]; }
    }
    if (t == 1023) rowptr[N] = part[1023];
}

__global__ void k_dis(const int* __restrict__ cnt, float* __restrict__ dis) {
    int i = blockIdx.x * blockDim.x + threadIdx.x;
    if (i < N) dis[i] = rsqrtf((float)cnt[i] + 1.0f);  // +1 self loop
}

__global__ void k_copy_int(const int* __restrict__ a, int* __restrict__ b, int n) {
    int i = blockIdx.x * blockDim.x + threadIdx.x;
    if (i < n) b[i] = a[i];
}

__global__ void k_scatter(const int* __restrict__ ei, const int* __restrict__ et,
                          int* __restrict__ cursor, int* __restrict__ csr_src,
                          int* __restrict__ csr_eid, int* __restrict__ csr_et) {
    int e = blockIdx.x * blockDim.x + threadIdx.x;
    if (e >= E) return;
    int d = ei[E + e];
    int pos = atomicAdd(&cursor[d], 1);
    csr_src[pos] = ei[e];
    csr_eid[pos] = e;
    csr_et[pos] = et[e];
}

// ---------------- GCN ----------------
// h1 = ccle0 @ W1   [N,32]
__global__ void k_h1(const float* __restrict__ x, const float* __restrict__ W,
                     float* __restrict__ h) {
    int idx = blockIdx.x * blockDim.x + threadIdx.x;
    if (idx >= N * 32) return;
    int n = idx >> 5, f = idx & 31;
    const float* xr = x + n * 4;
    float acc = 0.f;
#pragma unroll
    for (int c = 0; c < 4; ++c) acc += xr[c] * W[c * 32 + f];
    h[idx] = acc;
}

// c1[d][f] = dis[d] * sum_e dis[s]*h1[s][f] + dis[d]^2*h1[d][f] + b1[f]
__global__ void k_agg32(const int* __restrict__ rowptr, const int* __restrict__ csr_src,
                        const float* __restrict__ dis, const float* __restrict__ h,
                        const float* __restrict__ b, float* __restrict__ c) {
    int idx = blockIdx.x * blockDim.x + threadIdx.x;
    if (idx >= N * 32) return;
    int d = idx >> 5, f = idx & 31;
    int beg = rowptr[d], end = rowptr[d + 1];
    float acc = 0.f;
    for (int i = beg; i < end; ++i) {
        int s = csr_src[i];
        acc += dis[s] * h[s * 32 + f];
    }
    float dd = dis[d];
    c[idx] = dd * acc + dd * dd * h[idx] + b[f];
}

// h2 = leaky(c1) @ W2  [N,128]
__global__ void k_h2(const float* __restrict__ c1, const float* __restrict__ W,
                     float* __restrict__ h) {
    int idx = blockIdx.x * blockDim.x + threadIdx.x;
    if (idx >= N * 128) return;
    int n = idx >> 7, f = idx & 127;
    const float* cr = c1 + n * 32;
    float acc = 0.f;
    for (int c = 0; c < 32; ++c) acc += lrelu(cr[c], 0.01f) * W[c * 128 + f];
    h[idx] = acc;
}

__global__ void k_kgcopy(const float* __restrict__ kg, float* __restrict__ x0) {
    int idx = blockIdx.x * blockDim.x + threadIdx.x;
    if (idx >= N * 128) return;
    int n = idx >> 7, f = idx & 127;
    x0[n * 256 + f] = kg[idx];
}

__global__ void k_agg128(const int* __restrict__ rowptr, const int* __restrict__ csr_src,
                         const float* __restrict__ dis, const float* __restrict__ h,
                         const float* __restrict__ b, float* __restrict__ x0) {
    int idx = blockIdx.x * blockDim.x + threadIdx.x;
    if (idx >= N * 128) return;
    int d = idx >> 7, f = idx & 127;
    int beg = rowptr[d], end = rowptr[d + 1];
    float acc = 0.f;
    for (int i = beg; i < end; ++i) {
        int s = csr_src[i];
        acc += dis[s] * h[s * 128 + f];
    }
    float dd = dis[d];
    x0[d * 256 + 128 + f] = dd * acc + dd * dd * h[d * 128 + f] + b[f];
}

// ---------------- RGAT attention ----------------
// wq[i*32 + r*4 + h] = sum_o W[r][i][o]*q[o][h] ; same for wk
__global__ void k_wqk(const float* __restrict__ W, const float* __restrict__ q,
                      const float* __restrict__ kmat, float* __restrict__ wq,
                      float* __restrict__ wk) {
    int idx = blockIdx.x * blockDim.x + threadIdx.x;
    if (idx >= R * 256 * H) return;
    int r = idx >> 10, i = (idx >> 2) & 255, h = idx & 3;
    const float* wr = W + ((long)r * 256 + i) * 256;
    float aq = 0.f, ak = 0.f;
    for (int o = 0; o < 256; ++o) {
        float wv = wr[o];
        aq += wv * q[o * 4 + h];
        ak += wv * kmat[o * 4 + h];
    }
    wq[i * 32 + r * 4 + h] = aq;
    wk[i * 32 + r * 4 + h] = ak;
}

// qn[n*32 + r*4 + h] = x[n] . wq[:,r,h]
__global__ void k_qnkn(const float* __restrict__ x, const float* __restrict__ wq,
                       const float* __restrict__ wk, float* __restrict__ qn,
                       float* __restrict__ kn) {
    int idx = blockIdx.x * blockDim.x + threadIdx.x;
    if (idx >= N * 32) return;
    int n = idx >> 5, rh = idx & 31;
    const float* xr = x + (long)n * 256;
    float aq = 0.f, ak = 0.f;
    for (int i = 0; i < 256; ++i) {
        float xv = xr[i];
        aq += xv * wq[i * 32 + rh];
        ak += xv * wk[i * 32 + rh];
    }
    qn[idx] = aq;
    kn[idx] = ak;
}

__global__ void k_initmax(unsigned* __restrict__ amax, float* __restrict__ denom) {
    int idx = blockIdx.x * blockDim.x + threadIdx.x;
    if (idx < N * H) { amax[idx] = 0x007FFFFFu; denom[idx] = 0.f; }
}

__global__ void k_att1(const int* __restrict__ ei, const int* __restrict__ et,
                       const float* __restrict__ qn, const float* __restrict__ kn,
                       float* __restrict__ aout, unsigned* __restrict__ amax) {
    int idx = blockIdx.x * blockDim.x + threadIdx.x;
    if (idx >= E * H) return;
    int e = idx >> 2, h = idx & 3;
    int t = et[e], s = ei[e], d = ei[E + e];
    float v = qn[d * 32 + t * 4 + h] + kn[s * 32 + t * 4 + h];
    v = lrelu(v, 0.2f);
    aout[idx] = v;
    atomicMax(&amax[d * 4 + h], fenc(v));
}

__global__ void k_att2(const int* __restrict__ ei, float* __restrict__ aout,
                       const unsigned* __restrict__ amax, float* __restrict__ denom) {
    int idx = blockIdx.x * blockDim.x + threadIdx.x;
    if (idx >= E * H) return;
    int e = idx >> 2, h = idx & 3;
    int d = ei[E + e];
    float ex = expf(aout[idx] - fdec(amax[d * 4 + h]));
    aout[idx] = ex;
    atomicAdd(&denom[d * 4 + h], ex);
}

__global__ void k_att3(const int* __restrict__ ei, float* __restrict__ aout,
                       const float* __restrict__ denom) {
    int idx = blockIdx.x * blockDim.x + threadIdx.x;
    if (idx >= E * H) return;
    int e = idx >> 2, h = idx & 3;
    int d = ei[E + e];
    aout[idx] = aout[idx] / denom[d * 4 + h];
}

// ---------------- message aggregation (CSR gather, no atomics) ----------------
// one wave per dst node; lane covers 4 of the 256 features
__global__ void k_msg_gather(const int* __restrict__ rowptr, const int* __restrict__ csr_src,
                             const int* __restrict__ csr_eid, const int* __restrict__ csr_et,
                             const float* __restrict__ alpha, const float* __restrict__ xw,
                             const float* __restrict__ bias, float* __restrict__ out,
                             int r0, int r1, int first) {
    int gid = blockIdx.x * blockDim.x + threadIdx.x;
    int node = gid >> 6, lane = gid & 63;
    if (node >= N) return;
    float4 acc = {0.f, 0.f, 0.f, 0.f};
    int beg = rowptr[node], end = rowptr[node + 1];
    for (int i = beg; i < end; ++i) {
        int t = csr_et[i];
        if (t < r0 || t >= r1) continue;
        int s = csr_src[i];
        int eid = csr_eid[i];
        float a = alpha[(long)eid * 4 + (lane >> 4)];
        float4 v = ((const float4*)(xw + ((long)(t - r0) * N + s) * 256))[lane];
        acc.x += a * v.x; acc.y += a * v.y; acc.z += a * v.z; acc.w += a * v.w;
    }
    float* o = out + (long)node * 256 + lane * 4;
    if (first) {
        float4 b = ((const float4*)bias)[lane];
        o[0] = acc.x + b.x; o[1] = acc.y + b.y; o[2] = acc.z + b.z; o[3] = acc.w + b.w;
    } else {
        o[0] += acc.x; o[1] += acc.y; o[2] += acc.z; o[3] += acc.w;
    }
}

__global__ void k_leaky(float* p, int n) {
    int i = blockIdx.x * blockDim.x + threadIdx.x;
    if (i < n) p[i] = lrelu(p[i], 0.01f);
}

// ---------------- GEMM ----------------
// C[z] = A @ B[z] (+bias) (+C existing).  A:[M,K] row-major, B:[K,Nc], C:[M,Nc]
#define BM 64
#define BN 64
#define BKT 16
__global__ __launch_bounds__(256) void gemm_kernel(
    const float* __restrict__ A, const float* __restrict__ B,
    float* __restrict__ Cmat, const float* __restrict__ bias,
    int M, int K, int Nc, long strideB, long strideC, int addC)
{
    const float* Bp = B + (long)blockIdx.z * strideB;
    float* Cp = Cmat + (long)blockIdx.z * strideC;
    int m0 = blockIdx.y * BM;
    int n0 = blockIdx.x * BN;
    __shared__ float As[BKT][BM + 1];
    __shared__ float Bs[BKT][BN];
    int t = threadIdx.x;
    int tx = t & 15, ty = t >> 4;
    float acc[4][4] = {};
    for (int k0 = 0; k0 < K; k0 += BKT) {
#pragma unroll
        for (int i = 0; i < 4; ++i) {
            int idx = t + i * 256;
            int m = idx >> 4, kk = idx & 15;
            int gm = m0 + m;
            As[kk][m] = (gm < M) ? A[(long)gm * K + k0 + kk] : 0.f;
        }
#pragma unroll
        for (int i = 0; i < 4; ++i) {
            int idx = t + i * 256;
            int kk = idx >> 6, n = idx & 63;
            Bs[kk][n] = Bp[(long)(k0 + kk) * Nc + n0 + n];
        }
        __syncthreads();
#pragma unroll
        for (int kk = 0; kk < BKT; ++kk) {
            float ar[4], br[4];
#pragma unroll
            for (int i = 0; i < 4; ++i) ar[i] = As[kk][ty * 4 + i];
#pragma unroll
            for (int j = 0; j < 4; ++j) br[j] = Bs[kk][tx * 4 + j];
#pragma unroll
            for (int i = 0; i < 4; ++i)
#pragma unroll
                for (int j = 0; j < 4; ++j)
                    acc[i][j] += ar[i] * br[j];
        }
        __syncthreads();
    }
#pragma unroll
    for (int i = 0; i < 4; ++i) {
        int gm = m0 + ty * 4 + i;
        if (gm >= M) continue;
#pragma unroll
        for (int j = 0; j < 4; ++j) {
            int gn = n0 + tx * 4 + j;
            float v = acc[i][j];
            if (bias) v += bias[gn];
            if (addC) v += Cp[(long)gm * Nc + gn];
            Cp[(long)gm * Nc + gn] = v;
        }
    }
}

extern "C" void kernel_launch(void* const* d_in, const int* in_sizes, int n_in,
                              void* d_out, int out_size, void* d_ws, size_t ws_size,
                              hipStream_t stream) {
    const float* kg   = (const float*)d_in[0];
    const float* cc0  = (const float*)d_in[1];
    const float* gw1  = (const float*)d_in[2];
    const float* gb1  = (const float*)d_in[3];
    const float* gw2  = (const float*)d_in[4];
    const float* gb2  = (const float*)d_in[5];
    const float* r1w  = (const float*)d_in[6];
    const float* r1q  = (const float*)d_in[7];
    const float* r1k  = (const float*)d_in[8];
    const float* r1b  = (const float*)d_in[9];
    const float* r2w  = (const float*)d_in[10];
    const float* r2q  = (const float*)d_in[11];
    const float* r2k  = (const float*)d_in[12];
    const float* r2b  = (const float*)d_in[13];
    const float* linw = (const float*)d_in[14];
    const float* linb = (const float*)d_in[15];
    const int*   ei   = (const int*)d_in[16];
    const int*   et   = (const int*)d_in[17];

    float* out = (float*)d_out;
    float* a1  = out + (size_t)N * C;
    float* a2  = a1 + (size_t)E * H;

    float* ws = (float*)d_ws;
    size_t off = 0;
    float* dis  = ws + off; off += N;
    float* h1   = ws + off; off += (size_t)N * 32;
    float* c1   = ws + off; off += (size_t)N * 32;
    float* h2   = ws + off; off += (size_t)N * 128;
    float* x0   = ws + off; off += (size_t)N * C;
    float* hmid = ws + off; off += (size_t)N * C;
    float* qn   = ws + off; off += (size_t)N * R * H;
    float* kn   = ws + off; off += (size_t)N * R * H;
    float* wq   = ws + off; off += (size_t)R * 256 * H;
    float* wk   = ws + off; off += (size_t)R * 256 * H;
    unsigned* amax = (unsigned*)(ws + off); off += (size_t)N * H;
    float* denom = ws + off; off += (size_t)N * H;
    int* cnt     = (int*)(ws + off); off += N;
    int* rowptr  = (int*)(ws + off); off += N + 1;
    int* cursor  = (int*)(ws + off); off += N;
    int* csr_src = (int*)(ws + off); off += E;
    int* csr_eid = (int*)(ws + off); off += E;
    int* csr_et  = (int*)(ws + off); off += E;
    float* xw   = ws + off;

    size_t fixedB = off * 4;
    int K = R;  // relations materialized per chunk (shrinks if ws is small)
    if (ws_size > fixedB) {
        size_t kmax = (ws_size - fixedB) / ((size_t)N * C * 4);
        if (kmax < (size_t)K) K = (int)kmax;
    } else {
        K = 1;
    }
    if (K < 1) K = 1;

    const int B = 256;
    auto cdiv = [](long a, long b) { return (int)((a + b - 1) / b); };

    // ---- CSR build (shared by GCN + both RGAT layers) ----
    k_zero_int<<<cdiv(N, B), B, 0, stream>>>(cnt, N);
    k_count<<<cdiv(E, B), B, 0, stream>>>(ei, cnt);
    k_scan<<<1, 1024, 0, stream>>>(cnt, rowptr);
    k_dis<<<cdiv(N, B), B, 0, stream>>>(cnt, dis);
    k_copy_int<<<cdiv(N, B), B, 0, stream>>>(rowptr, cursor, N);
    k_scatter<<<cdiv(E, B), B, 0, stream>>>(ei, et, cursor, csr_src, csr_eid, csr_et);

    // ---- GCN1: 4->32 ----
    k_h1<<<cdiv((long)N * 32, B), B, 0, stream>>>(cc0, gw1, h1);
    k_agg32<<<cdiv((long)N * 32, B), B, 0, stream>>>(rowptr, csr_src, dis, h1, gb1, c1);
    // ---- GCN2: 32->128 (leaky fused into k_h2 read) ----
    k_h2<<<cdiv((long)N * 128, B), B, 0, stream>>>(c1, gw2, h2);
    k_kgcopy<<<cdiv((long)N * 128, B), B, 0, stream>>>(kg, x0);
    k_agg128<<<cdiv((long)N * 128, B), B, 0, stream>>>(rowptr, csr_src, dis, h2, gb2, x0);

    auto rgat = [&](const float* xin, const float* W, const float* q, const float* kk,
                    const float* b, float* obuf, float* aout) {
        k_wqk<<<cdiv((long)R * 256 * H, B), B, 0, stream>>>(W, q, kk, wq, wk);
        k_qnkn<<<cdiv((long)N * R * H, B), B, 0, stream>>>(xin, wq, wk, qn, kn);
        k_initmax<<<cdiv((long)N * H, B), B, 0, stream>>>(amax, denom);
        k_att1<<<cdiv((long)E * H, B), B, 0, stream>>>(ei, et, qn, kn, aout, amax);
        k_att2<<<cdiv((long)E * H, B), B, 0, stream>>>(ei, aout, amax, denom);
        k_att3<<<cdiv((long)E * H, B), B, 0, stream>>>(ei, aout, denom);
        for (int r0 = 0; r0 < R; r0 += K) {
            int kc = (R - r0) < K ? (R - r0) : K;
            dim3 g(C / 64, cdiv(N, 64), kc);
            gemm_kernel<<<g, 256, 0, stream>>>(xin, W + (long)r0 * C * C, xw, nullptr,
                                               N, C, C, (long)C * C, (long)N * C, 0);
            k_msg_gather<<<cdiv((long)N * 64, B), B, 0, stream>>>(
                rowptr, csr_src, csr_eid, csr_et, aout, xw, b, obuf,
                r0, r0 + kc, r0 == 0 ? 1 : 0);
        }
    };

    rgat(x0, r1w, r1q, r1k, r1b, hmid, a1);
    k_leaky<<<cdiv((long)N * C, B), B, 0, stream>>>(hmid, N * C);
    rgat(hmid, r2w, r2q, r2k, r2b, out, a2);

    // out += x0 @ lin_w + lin_b
    dim3 g(C / 64, cdiv(N, 64), 1);
    gemm_kernel<<<g, 256, 0, stream>>>(x0, linw, out, linb, N, C, C, 0, 0, 1);
}

// Round 3
// 870.942 us; speedup vs baseline: 3.9378x; 1.6010x over previous
//
#include <hip/hip_runtime.h>
#include <cstdint>

static constexpr int N = 20000;
static constexpr int E = 320000;
static constexpr int R = 8;
static constexpr int H = 4;
static constexpr int C = 256;

using short8 = __attribute__((ext_vector_type(8))) short;
using f32x4  = __attribute__((ext_vector_type(4))) float;

__device__ __forceinline__ float lrelu(float x, float s) { return x >= 0.f ? x : s * x; }
__device__ __forceinline__ unsigned fenc(float f) {
    unsigned u = __float_as_uint(f);
    return (u & 0x80000000u) ? ~u : (u | 0x80000000u);
}
__device__ __forceinline__ float fdec(unsigned u) {
    unsigned v = (u & 0x80000000u) ? (u & 0x7FFFFFFFu) : ~u;
    return __uint_as_float(v);
}
__device__ __forceinline__ unsigned short f2bf(float f) {
    unsigned u = __float_as_uint(f);
    unsigned r = (u + 0x7FFFu + ((u >> 16) & 1u)) >> 16;
    return (unsigned short)r;
}

// ---------------- CSR build ----------------
__global__ void k_zero_int(int* p, int n) {
    int i = blockIdx.x * blockDim.x + threadIdx.x;
    if (i < n) p[i] = 0;
}

__global__ void k_count(const int* __restrict__ ei, int* __restrict__ cnt) {
    int e = blockIdx.x * blockDim.x + threadIdx.x;
    if (e < E) atomicAdd(&cnt[ei[E + e]], 1);
}

__global__ __launch_bounds__(1024) void k_scan(const int* __restrict__ cnt,
                                               int* __restrict__ rowptr) {
    __shared__ int part[1024];
    const int CH = (N + 1023) / 1024;  // 20
    int t = threadIdx.x;
    int base = t * CH;
    int sum = 0;
    for (int j = 0; j < CH; ++j) {
        int idx = base + j;
        if (idx < N) sum += cnt[idx];
    }
    part[t] = sum;
    __syncthreads();
    for (int off = 1; off < 1024; off <<= 1) {
        int v = 0;
        if (t >= off) v = part[t - off];
        __syncthreads();
        if (t >= off) part[t] += v;
        __syncthreads();
    }
    int run = part[t] - sum;
    for (int j = 0; j < CH; ++j) {
        int idx = base + j;
        if (idx < N) { rowptr[idx] = run; run += cnt[idx]; }
    }
    if (t == 1023) rowptr[N] = part[1023];
}

__global__ void k_dis(const int* __restrict__ cnt, float* __restrict__ dis) {
    int i = blockIdx.x * blockDim.x + threadIdx.x;
    if (i < N) dis[i] = rsqrtf((float)cnt[i] + 1.0f);
}

__global__ void k_copy_int(const int* __restrict__ a, int* __restrict__ b, int n) {
    int i = blockIdx.x * blockDim.x + threadIdx.x;
    if (i < n) b[i] = a[i];
}

__global__ void k_scatter(const int* __restrict__ ei, const int* __restrict__ et,
                          int* __restrict__ cursor, int* __restrict__ csr_src,
                          int* __restrict__ csr_eid, int* __restrict__ csr_et) {
    int e = blockIdx.x * blockDim.x + threadIdx.x;
    if (e >= E) return;
    int d = ei[E + e];
    int pos = atomicAdd(&cursor[d], 1);
    csr_src[pos] = ei[e];
    csr_eid[pos] = e;
    csr_et[pos] = et[e];
}

// ---------------- GCN ----------------
__global__ void k_h1(const float* __restrict__ x, const float* __restrict__ W,
                     float* __restrict__ h) {
    int idx = blockIdx.x * blockDim.x + threadIdx.x;
    if (idx >= N * 32) return;
    int n = idx >> 5, f = idx & 31;
    const float* xr = x + n * 4;
    float acc = 0.f;
#pragma unroll
    for (int c = 0; c < 4; ++c) acc += xr[c] * W[c * 32 + f];
    h[idx] = acc;
}

__global__ void k_agg32(const int* __restrict__ rowptr, const int* __restrict__ csr_src,
                        const float* __restrict__ dis, const float* __restrict__ h,
                        const float* __restrict__ b, float* __restrict__ c) {
    int idx = blockIdx.x * blockDim.x + threadIdx.x;
    if (idx >= N * 32) return;
    int d = idx >> 5, f = idx & 31;
    int beg = rowptr[d], end = rowptr[d + 1];
    float acc = 0.f;
    for (int i = beg; i < end; ++i) {
        int s = csr_src[i];
        acc += dis[s] * h[s * 32 + f];
    }
    float dd = dis[d];
    c[idx] = dd * acc + dd * dd * h[idx] + b[f];
}

__global__ void k_h2(const float* __restrict__ c1, const float* __restrict__ W,
                     float* __restrict__ h) {
    int idx = blockIdx.x * blockDim.x + threadIdx.x;
    if (idx >= N * 128) return;
    int n = idx >> 7, f = idx & 127;
    const float* cr = c1 + n * 32;
    float acc = 0.f;
    for (int c = 0; c < 32; ++c) acc += lrelu(cr[c], 0.01f) * W[c * 128 + f];
    h[idx] = acc;
}

__global__ void k_kgcopy(const float* __restrict__ kg, float* __restrict__ x0) {
    int idx = blockIdx.x * blockDim.x + threadIdx.x;
    if (idx >= N * 128) return;
    int n = idx >> 7, f = idx & 127;
    x0[n * 256 + f] = kg[idx];
}

__global__ void k_agg128(const int* __restrict__ rowptr, const int* __restrict__ csr_src,
                         const float* __restrict__ dis, const float* __restrict__ h,
                         const float* __restrict__ b, float* __restrict__ x0) {
    int idx = blockIdx.x * blockDim.x + threadIdx.x;
    if (idx >= N * 128) return;
    int d = idx >> 7, f = idx & 127;
    int beg = rowptr[d], end = rowptr[d + 1];
    float acc = 0.f;
    for (int i = beg; i < end; ++i) {
        int s = csr_src[i];
        acc += dis[s] * h[s * 128 + f];
    }
    float dd = dis[d];
    x0[d * 256 + 128 + f] = dd * acc + dd * dd * h[d * 128 + f] + b[f];
}

// ---------------- RGAT attention ----------------
__global__ void k_wqk(const float* __restrict__ W, const float* __restrict__ q,
                      const float* __restrict__ kmat, float* __restrict__ wq,
                      float* __restrict__ wk) {
    int idx = blockIdx.x * blockDim.x + threadIdx.x;
    if (idx >= R * 256 * H) return;
    int r = idx >> 10, i = (idx >> 2) & 255, h = idx & 3;
    const float* wr = W + ((long)r * 256 + i) * 256;
    float aq = 0.f, ak = 0.f;
    for (int o = 0; o < 256; ++o) {
        float wv = wr[o];
        aq += wv * q[o * 4 + h];
        ak += wv * kmat[o * 4 + h];
    }
    wq[i * 32 + r * 4 + h] = aq;
    wk[i * 32 + r * 4 + h] = ak;
}

__global__ void k_qnkn(const float* __restrict__ x, const float* __restrict__ wq,
                       const float* __restrict__ wk, float* __restrict__ qn,
                       float* __restrict__ kn) {
    int idx = blockIdx.x * blockDim.x + threadIdx.x;
    if (idx >= N * 32) return;
    int n = idx >> 5, rh = idx & 31;
    const float* xr = x + (long)n * 256;
    float aq = 0.f, ak = 0.f;
    for (int i = 0; i < 256; ++i) {
        float xv = xr[i];
        aq += xv * wq[i * 32 + rh];
        ak += xv * wk[i * 32 + rh];
    }
    qn[idx] = aq;
    kn[idx] = ak;
}

__global__ void k_initmax(unsigned* __restrict__ amax, float* __restrict__ denom) {
    int idx = blockIdx.x * blockDim.x + threadIdx.x;
    if (idx < N * H) { amax[idx] = 0x007FFFFFu; denom[idx] = 0.f; }
}

__global__ void k_att1(const int* __restrict__ ei, const int* __restrict__ et,
                       const float* __restrict__ qn, const float* __restrict__ kn,
                       float* __restrict__ aout, unsigned* __restrict__ amax) {
    int idx = blockIdx.x * blockDim.x + threadIdx.x;
    if (idx >= E * H) return;
    int e = idx >> 2, h = idx & 3;
    int t = et[e], s = ei[e], d = ei[E + e];
    float v = qn[d * 32 + t * 4 + h] + kn[s * 32 + t * 4 + h];
    v = lrelu(v, 0.2f);
    aout[idx] = v;
    atomicMax(&amax[d * 4 + h], fenc(v));
}

__global__ void k_att2(const int* __restrict__ ei, float* __restrict__ aout,
                       const unsigned* __restrict__ amax, float* __restrict__ denom) {
    int idx = blockIdx.x * blockDim.x + threadIdx.x;
    if (idx >= E * H) return;
    int e = idx >> 2, h = idx & 3;
    int d = ei[E + e];
    float ex = expf(aout[idx] - fdec(amax[d * 4 + h]));
    aout[idx] = ex;
    atomicAdd(&denom[d * 4 + h], ex);
}

__global__ void k_att3(const int* __restrict__ ei, float* __restrict__ aout,
                       const float* __restrict__ denom) {
    int idx = blockIdx.x * blockDim.x + threadIdx.x;
    if (idx >= E * H) return;
    int e = idx >> 2, h = idx & 3;
    int d = ei[E + e];
    aout[idx] = aout[idx] / denom[d * 4 + h];
}

// ---------------- bf16 conversion / transpose ----------------
__global__ void k_xconv(const float* __restrict__ x, unsigned short* __restrict__ xb) {
    int idx = blockIdx.x * blockDim.x + threadIdx.x;
    if (idx < N * 256) xb[idx] = f2bf(x[idx]);
}

// Wt[z][n][k] = bf16(W[z][k][n])
__global__ void k_wconv(const float* __restrict__ W, unsigned short* __restrict__ Wt) {
    int idx = blockIdx.x * blockDim.x + threadIdx.x;
    if (idx >= R * 256 * 256) return;
    int z = idx >> 16, k = (idx >> 8) & 255, n = idx & 255;
    float v = W[((size_t)z << 16) + (k << 8) + n];
    Wt[((size_t)z << 16) + (n << 8) + k] = f2bf(v);
}

// ---------------- bf16 MFMA GEMM: xw[z] = x @ W[z] ----------------
// A: [M][256] bf16 row-major; Bt: [z][256(n)][256(k)] bf16; Cw: [z][M][256] bf16
#define GBM 128
#define GBN 128
#define GBK 32
#define LDAP 40  // padded LDS pitch in bf16 (32 + 8): keeps 16B alignment, 2-way banks
__global__ __launch_bounds__(256) void gemm_mfma(
    const unsigned short* __restrict__ A, const unsigned short* __restrict__ Bt,
    unsigned short* __restrict__ Cw, int M)
{
    __shared__ unsigned short As[GBM * LDAP];
    __shared__ unsigned short Bs[GBN * LDAP];
    int z = blockIdx.z;
    int m0 = blockIdx.y * GBM;
    int n0 = blockIdx.x * GBN;
    const unsigned short* Bz = Bt + ((size_t)z << 16);
    int t = threadIdx.x;
    int wave = t >> 6, lane = t & 63;
    int wr = wave >> 1, wc = wave & 1;
    int lrow = lane & 15, kq = lane >> 4;

    f32x4 acc[4][4];
#pragma unroll
    for (int i = 0; i < 4; ++i)
#pragma unroll
        for (int j = 0; j < 4; ++j) acc[i][j] = (f32x4){0.f, 0.f, 0.f, 0.f};

    for (int k0 = 0; k0 < 256; k0 += GBK) {
        // stage A/B tiles: 512 chunks of 8 bf16 each, 2 per thread per matrix
#pragma unroll
        for (int i = 0; i < 2; ++i) {
            int c = t + i * 256;
            int row = c >> 2, kc = c & 3;
            int gm = m0 + row;
            uint4 va = {0, 0, 0, 0};
            if (gm < M) va = *(const uint4*)(A + (size_t)gm * 256 + k0 + kc * 8);
            *(uint4*)(As + row * LDAP + kc * 8) = va;
            uint4 vb = *(const uint4*)(Bz + (size_t)(n0 + row) * 256 + k0 + kc * 8);
            *(uint4*)(Bs + row * LDAP + kc * 8) = vb;
        }
        __syncthreads();
        short8 af[4], bf[4];
#pragma unroll
        for (int i = 0; i < 4; ++i)
            af[i] = *(const short8*)(As + (wr * 64 + i * 16 + lrow) * LDAP + kq * 8);
#pragma unroll
        for (int j = 0; j < 4; ++j)
            bf[j] = *(const short8*)(Bs + (wc * 64 + j * 16 + lrow) * LDAP + kq * 8);
#pragma unroll
        for (int i = 0; i < 4; ++i)
#pragma unroll
            for (int j = 0; j < 4; ++j)
                acc[i][j] = __builtin_amdgcn_mfma_f32_16x16x32_bf16(af[i], bf[j],
                                                                   acc[i][j], 0, 0, 0);
        __syncthreads();
    }
    // C/D layout: row = quad*4 + reg, col = lane&15
#pragma unroll
    for (int i = 0; i < 4; ++i) {
#pragma unroll
        for (int j = 0; j < 4; ++j) {
            int gn = n0 + wc * 64 + j * 16 + lrow;
#pragma unroll
            for (int reg = 0; reg < 4; ++reg) {
                int gm = m0 + wr * 64 + i * 16 + kq * 4 + reg;
                if (gm < M) Cw[((size_t)z * M + gm) * 256 + gn] = f2bf(acc[i][j][reg]);
            }
        }
    }
}

// ---------------- message aggregation (CSR gather, bf16 xw) ----------------
__global__ void k_msg_gather(const int* __restrict__ rowptr, const int* __restrict__ csr_src,
                             const int* __restrict__ csr_eid, const int* __restrict__ csr_et,
                             const float* __restrict__ alpha,
                             const unsigned short* __restrict__ xw,
                             const float* __restrict__ bias, float* __restrict__ out,
                             int r0, int r1, int first) {
    int gid = blockIdx.x * blockDim.x + threadIdx.x;
    int node = gid >> 6, lane = gid & 63;
    if (node >= N) return;
    float ax = 0.f, ay = 0.f, az = 0.f, aw = 0.f;
    int beg = rowptr[node], end = rowptr[node + 1];
    for (int i = beg; i < end; ++i) {
        int t = csr_et[i];
        if (t < r0 || t >= r1) continue;
        int s = csr_src[i];
        int eid = csr_eid[i];
        float a = alpha[(long)eid * 4 + (lane >> 4)];
        uint2 p = *(const uint2*)(xw + ((size_t)(t - r0) * N + s) * 256 + lane * 4);
        ax += a * __uint_as_float(p.x << 16);
        ay += a * __uint_as_float(p.x & 0xFFFF0000u);
        az += a * __uint_as_float(p.y << 16);
        aw += a * __uint_as_float(p.y & 0xFFFF0000u);
    }
    float* o = out + (size_t)node * 256 + lane * 4;
    if (first) {
        const float4 b = ((const float4*)bias)[lane];
        o[0] = ax + b.x; o[1] = ay + b.y; o[2] = az + b.z; o[3] = aw + b.w;
    } else {
        o[0] += ax; o[1] += ay; o[2] += az; o[3] += aw;
    }
}

__global__ void k_leaky(float* p, int n) {
    int i = blockIdx.x * blockDim.x + threadIdx.x;
    if (i < n) p[i] = lrelu(p[i], 0.01f);
}

// ---------------- fp32 GEMM (final linear only) ----------------
#define BM 64
#define BN 64
#define BKT 16
__global__ __launch_bounds__(256) void gemm_kernel(
    const float* __restrict__ A, const float* __restrict__ B,
    float* __restrict__ Cmat, const float* __restrict__ bias,
    int M, int K, int Nc, long strideB, long strideC, int addC)
{
    const float* Bp = B + (long)blockIdx.z * strideB;
    float* Cp = Cmat + (long)blockIdx.z * strideC;
    int m0 = blockIdx.y * BM;
    int n0 = blockIdx.x * BN;
    __shared__ float As[BKT][BM + 1];
    __shared__ float Bs[BKT][BN];
    int t = threadIdx.x;
    int tx = t & 15, ty = t >> 4;
    float acc[4][4] = {};
    for (int k0 = 0; k0 < K; k0 += BKT) {
#pragma unroll
        for (int i = 0; i < 4; ++i) {
            int idx = t + i * 256;
            int m = idx >> 4, kk = idx & 15;
            int gm = m0 + m;
            As[kk][m] = (gm < M) ? A[(long)gm * K + k0 + kk] : 0.f;
        }
#pragma unroll
        for (int i = 0; i < 4; ++i) {
            int idx = t + i * 256;
            int kk = idx >> 6, n = idx & 63;
            Bs[kk][n] = Bp[(long)(k0 + kk) * Nc + n0 + n];
        }
        __syncthreads();
#pragma unroll
        for (int kk = 0; kk < BKT; ++kk) {
            float ar[4], br[4];
#pragma unroll
            for (int i = 0; i < 4; ++i) ar[i] = As[kk][ty * 4 + i];
#pragma unroll
            for (int j = 0; j < 4; ++j) br[j] = Bs[kk][tx * 4 + j];
#pragma unroll
            for (int i = 0; i < 4; ++i)
#pragma unroll
                for (int j = 0; j < 4; ++j)
                    acc[i][j] += ar[i] * br[j];
        }
        __syncthreads();
    }
#pragma unroll
    for (int i = 0; i < 4; ++i) {
        int gm = m0 + ty * 4 + i;
        if (gm >= M) continue;
#pragma unroll
        for (int j = 0; j < 4; ++j) {
            int gn = n0 + tx * 4 + j;
            float v = acc[i][j];
            if (bias) v += bias[gn];
            if (addC) v += Cp[(long)gm * Nc + gn];
            Cp[(long)gm * Nc + gn] = v;
        }
    }
}

extern "C" void kernel_launch(void* const* d_in, const int* in_sizes, int n_in,
                              void* d_out, int out_size, void* d_ws, size_t ws_size,
                              hipStream_t stream) {
    const float* kg   = (const float*)d_in[0];
    const float* cc0  = (const float*)d_in[1];
    const float* gw1  = (const float*)d_in[2];
    const float* gb1  = (const float*)d_in[3];
    const float* gw2  = (const float*)d_in[4];
    const float* gb2  = (const float*)d_in[5];
    const float* r1w  = (const float*)d_in[6];
    const float* r1q  = (const float*)d_in[7];
    const float* r1k  = (const float*)d_in[8];
    const float* r1b  = (const float*)d_in[9];
    const float* r2w  = (const float*)d_in[10];
    const float* r2q  = (const float*)d_in[11];
    const float* r2k  = (const float*)d_in[12];
    const float* r2b  = (const float*)d_in[13];
    const float* linw = (const float*)d_in[14];
    const float* linb = (const float*)d_in[15];
    const int*   ei   = (const int*)d_in[16];
    const int*   et   = (const int*)d_in[17];

    float* out = (float*)d_out;
    float* a1  = out + (size_t)N * C;
    float* a2  = a1 + (size_t)E * H;

    float* ws = (float*)d_ws;
    size_t off = 0;
    float* dis  = ws + off; off += N;
    float* h1   = ws + off; off += (size_t)N * 32;
    float* c1   = ws + off; off += (size_t)N * 32;
    float* h2   = ws + off; off += (size_t)N * 128;
    float* x0   = ws + off; off += (size_t)N * C;
    float* hmid = ws + off; off += (size_t)N * C;
    float* qn   = ws + off; off += (size_t)N * R * H;
    float* kn   = ws + off; off += (size_t)N * R * H;
    float* wq   = ws + off; off += (size_t)R * 256 * H;
    float* wk   = ws + off; off += (size_t)R * 256 * H;
    unsigned* amax = (unsigned*)(ws + off); off += (size_t)N * H;
    float* denom = ws + off; off += (size_t)N * H;
    int* cnt     = (int*)(ws + off); off += N;
    int* rowptr  = (int*)(ws + off); off += N + 1;
    int* cursor  = (int*)(ws + off); off += N;
    int* csr_src = (int*)(ws + off); off += E;
    int* csr_eid = (int*)(ws + off); off += E;
    int* csr_et  = (int*)(ws + off); off += E;
    unsigned short* xb = (unsigned short*)(ws + off); off += (size_t)N * 128;   // N*256 bf16
    unsigned short* wt = (unsigned short*)(ws + off); off += (size_t)R * 128 * 256; // R*64K bf16
    unsigned short* xwb = (unsigned short*)(ws + off);

    size_t fixedB = off * 4;
    int K = R;  // relations materialized per chunk
    if (ws_size > fixedB) {
        size_t kmax = (ws_size - fixedB) / ((size_t)N * C * 2);
        if (kmax < (size_t)K) K = (int)kmax;
    } else {
        K = 1;
    }
    if (K < 1) K = 1;

    const int B = 256;
    auto cdiv = [](long a, long b) { return (int)((a + b - 1) / b); };

    // ---- CSR build ----
    k_zero_int<<<cdiv(N, B), B, 0, stream>>>(cnt, N);
    k_count<<<cdiv(E, B), B, 0, stream>>>(ei, cnt);
    k_scan<<<1, 1024, 0, stream>>>(cnt, rowptr);
    k_dis<<<cdiv(N, B), B, 0, stream>>>(cnt, dis);
    k_copy_int<<<cdiv(N, B), B, 0, stream>>>(rowptr, cursor, N);
    k_scatter<<<cdiv(E, B), B, 0, stream>>>(ei, et, cursor, csr_src, csr_eid, csr_et);

    // ---- GCN ----
    k_h1<<<cdiv((long)N * 32, B), B, 0, stream>>>(cc0, gw1, h1);
    k_agg32<<<cdiv((long)N * 32, B), B, 0, stream>>>(rowptr, csr_src, dis, h1, gb1, c1);
    k_h2<<<cdiv((long)N * 128, B), B, 0, stream>>>(c1, gw2, h2);
    k_kgcopy<<<cdiv((long)N * 128, B), B, 0, stream>>>(kg, x0);
    k_agg128<<<cdiv((long)N * 128, B), B, 0, stream>>>(rowptr, csr_src, dis, h2, gb2, x0);

    auto rgat = [&](const float* xin, const float* W, const float* q, const float* kk,
                    const float* b, float* obuf, float* aout) {
        k_wqk<<<cdiv((long)R * 256 * H, B), B, 0, stream>>>(W, q, kk, wq, wk);
        k_qnkn<<<cdiv((long)N * R * H, B), B, 0, stream>>>(xin, wq, wk, qn, kn);
        k_initmax<<<cdiv((long)N * H, B), B, 0, stream>>>(amax, denom);
        k_att1<<<cdiv((long)E * H, B), B, 0, stream>>>(ei, et, qn, kn, aout, amax);
        k_att2<<<cdiv((long)E * H, B), B, 0, stream>>>(ei, aout, amax, denom);
        k_att3<<<cdiv((long)E * H, B), B, 0, stream>>>(ei, aout, denom);
        k_xconv<<<cdiv((long)N * 256, B), B, 0, stream>>>(xin, xb);
        k_wconv<<<cdiv((long)R * 256 * 256, B), B, 0, stream>>>(W, wt);
        for (int r0 = 0; r0 < R; r0 += K) {
            int kc = (R - r0) < K ? (R - r0) : K;
            dim3 g(C / GBN, cdiv(N, GBM), kc);
            gemm_mfma<<<g, 256, 0, stream>>>(xb, wt + ((size_t)r0 << 16), xwb, N);
            k_msg_gather<<<cdiv((long)N * 64, B), B, 0, stream>>>(
                rowptr, csr_src, csr_eid, csr_et, aout, xwb, b, obuf,
                r0, r0 + kc, r0 == 0 ? 1 : 0);
        }
    };

    rgat(x0, r1w, r1q, r1k, r1b, hmid, a1);
    k_leaky<<<cdiv((long)N * C, B), B, 0, stream>>>(hmid, N * C);
    rgat(hmid, r2w, r2q, r2k, r2b, out, a2);

    // out += x0 @ lin_w + lin_b
    dim3 g(C / BN, cdiv(N, BM), 1);
    gemm_kernel<<<g, 256, 0, stream>>>(x0, linw, out, linb, N, C, C, 0, 0, 1);
}